// Round 7
// baseline (1237.466 us; speedup 1.0000x reference)
//
#include <hip/hip_runtime.h>
#include <stdint.h>

// HistMatching via stable LSD radix sort (4 x 8-bit passes) of (key32,idx32)
// u64 pairs per segment. Stability via per-(bin,block) histogram matrix +
// exclusive scan. Final pass fuses the epilogue: template -> tsorted[dest]=val;
// samples -> out[idx]=tsorted[dest].
//
// R1: part_k single-LDS-buffer in-place split (4x2-bit rounds), run-boundary
//     starts, hoisted base gather. 117us/dispatch verified.
// R2 (REVERTED): per-element global atomics for fused hist (+575us/pass).
// R3 (REVERTED): onesweep — tile-hist LDS atomics on skewed digits too slow.
// R4 (REVERTED): SoA keys/idx — split scattered writes regressed part_k.
// R5: scanT_k (fused transpose+scan via lookback) KEPT (dispatch-count win).
// R6 (REVERTED): ballot-waterfall hist — serial shfl/ballot loop cost more
//     than the LDS-atomic serialization it removed.
// R7: TILE 4096 -> 8192. Doubles the average digit-run length (128B -> 256B
//     contiguous write segments; each 64-lane store touches ~2 regions not
//     ~4), halves per-block overhead (base gather, boundaries, 5760->2880
//     blocks) and halves the scan matrix. LDS 71.7KB -> 2 blocks/CU, an axis
//     measured to cost only ~6% (R0 vs R1); write efficiency is the bet.

#define SEG_N 2621440            // 128*160*128
#define NSEG 9                   // template + 8 samples
#define TILE 8192
#define NBLK (SEG_N / TILE)      // 320 blocks per segment
#define RADIX 256
#define HL (RADIX * NBLK)        // 81920 histogram-matrix entries per seg
#define SCHUNK 4096
#define SNB (HL / SCHUNK)        // 20 scan chunks per seg
#define SBUF (TILE + (TILE >> 4))  // 8704 u64, padded 1-per-16
#define EPT 32                   // elements per thread in part_k

// monotone f32 -> u32 (order-preserving)
__device__ __forceinline__ uint32_t fkey(float f) {
  uint32_t b = __float_as_uint(f);
  return b ^ ((b & 0x80000000u) ? 0xFFFFFFFFu : 0x80000000u);
}
__device__ __forceinline__ float finv(uint32_t u) {
  uint32_t b = u ^ ((u & 0x80000000u) ? 0x80000000u : 0xFFFFFFFFu);
  return __uint_as_float(b);
}
__device__ __forceinline__ uint32_t SIDX(uint32_t i) { return i + (i >> 4); }

// ---------- init: build pairsA in index order + digit-0 histogram ----------
__global__ __launch_bounds__(256) void init_k(const float* __restrict__ x,
                                              const float* __restrict__ tmpl,
                                              int segbase,
                                              uint64_t* __restrict__ pairsA,
                                              uint32_t* __restrict__ Hkb) {
  __shared__ uint32_t hw[4 * RADIX];   // per-wave replicated
  const int t = threadIdx.x;
  const int blk = blockIdx.x;
  const int sl = blockIdx.y;
  const int seg = segbase + sl;
  const float* src = (seg == 0) ? tmpl : (x + (size_t)(seg - 1) * SEG_N);
  uint64_t* pa = pairsA + (size_t)sl * SEG_N;
  hw[t] = 0; hw[t + 256] = 0; hw[t + 512] = 0; hw[t + 768] = 0;
  __syncthreads();
  const int w = t >> 6;
  const uint32_t base = blk * TILE;
  const float4* s4 = reinterpret_cast<const float4*>(src + base);
#pragma unroll
  for (int r = 0; r < TILE / 1024; ++r) {
    float4 v = s4[r * 256 + t];
    uint32_t i0 = base + (uint32_t)(r * 256 + t) * 4u;
    float f[4] = {v.x, v.y, v.z, v.w};
#pragma unroll
    for (int c = 0; c < 4; ++c) {
      uint32_t k = fkey(f[c]);
      atomicAdd(&hw[w * 256 + (k & 255u)], 1u);
      pa[i0 + c] = ((uint64_t)k << 32) | (uint64_t)(i0 + c);
    }
  }
  __syncthreads();
  Hkb[(size_t)sl * HL + (size_t)blk * RADIX + t] =
      hw[t] + hw[t + 256] + hw[t + 512] + hw[t + 768];   // [blk][bin]
}

// ---------- histogram of digit p over current pairs ----------
__global__ __launch_bounds__(256) void hist_k(const uint64_t* __restrict__ pairs,
                                              uint32_t* __restrict__ Hkb, int p) {
  __shared__ uint32_t hw[4 * RADIX];   // per-wave replicated
  const int t = threadIdx.x;
  const int blk = blockIdx.x;
  const int sl = blockIdx.y;
  hw[t] = 0; hw[t + 256] = 0; hw[t + 512] = 0; hw[t + 768] = 0;
  __syncthreads();
  const int w = t >> 6;
  const int sh = 32 + 8 * p;
  const ulonglong2* pc = reinterpret_cast<const ulonglong2*>(
      pairs + (size_t)sl * SEG_N + (size_t)blk * TILE);
#pragma unroll
  for (int r = 0; r < TILE / 512; ++r) {
    ulonglong2 v = pc[r * 256 + t];
    atomicAdd(&hw[w * 256 + ((uint32_t)(v.x >> sh) & 255u)], 1u);
    atomicAdd(&hw[w * 256 + ((uint32_t)(v.y >> sh) & 255u)], 1u);
  }
  __syncthreads();
  Hkb[(size_t)sl * HL + (size_t)blk * RADIX + t] =
      hw[t] + hw[t + 256] + hw[t + 512] + hw[t + 768];
}

// ---------- fused transpose-read + scan via decoupled lookback ----------
// Scans the conceptual transposed sequence e=bin*NBLK+blk (exclusive) from
// Hkb [blk][bin] into Hbk [bin][blk]. 20 chunks/segment, all blocks
// co-resident => flag-spin lookback is deadlock-free.
// desc word = flag[31:30] | value[29:0], relaxed agent-scope.
__global__ __launch_bounds__(256) void scanT_k(const uint32_t* __restrict__ Hkb,
                                               uint32_t* __restrict__ Hbk,
                                               uint32_t* __restrict__ desc) {
  __shared__ uint32_t lds[256];
  __shared__ uint32_t baseS;
  const int t = threadIdx.x;
  const int c = blockIdx.x;          // 0..SNB-1
  const int sl = blockIdx.y;
  const uint32_t* src = Hkb + (size_t)sl * HL;
  const uint32_t e0 = (uint32_t)c * SCHUNK + (uint32_t)t * 16;
  uint32_t vals[16];
  uint32_t s = 0;
#pragma unroll
  for (int i = 0; i < 16; ++i) {
    uint32_t e = e0 + (uint32_t)i;
    uint32_t bin = e / NBLK, blk = e - bin * NBLK;
    vals[i] = src[(size_t)blk * RADIX + bin];
    s += vals[i];
  }
  // block-wide exclusive scan of per-thread sums (Hillis-Steele)
  lds[t] = s;
  __syncthreads();
#pragma unroll
  for (int off = 1; off < 256; off <<= 1) {
    uint32_t a = (t >= off) ? lds[t - off] : 0u;
    __syncthreads();
    lds[t] += a;
    __syncthreads();
  }
  const uint32_t incl = lds[t];
  const uint32_t total = lds[255];
  const uint32_t ex = incl - s;

  uint32_t* dseg = desc + sl * SNB;
  if (t == 0) {
    __hip_atomic_store(&dseg[c], (total & 0x3FFFFFFFu) |
                                     ((c == 0 ? 2u : 1u) << 30),
                       __ATOMIC_RELAXED, __HIP_MEMORY_SCOPE_AGENT);
    uint32_t acc = 0;
    if (c > 0) {
      int b = c - 1;
      bool done = false;
      while (!done) {
        uint32_t dv[8];
        const int n = (b >= 7) ? 8 : (b + 1);
#pragma unroll
        for (int i = 0; i < 8; ++i)
          if (i < n)
            dv[i] = __hip_atomic_load(&dseg[b - i], __ATOMIC_RELAXED,
                                      __HIP_MEMORY_SCOPE_AGENT);
        for (int i = 0; i < n; ++i) {
          uint32_t v = dv[i];
          while ((v >> 30) == 0u)
            v = __hip_atomic_load(&dseg[b - i], __ATOMIC_RELAXED,
                                  __HIP_MEMORY_SCOPE_AGENT);
          acc += v & 0x3FFFFFFFu;
          if ((v >> 30) == 2u) { done = true; break; }
        }
        b -= n;
        if (!done && b < 0) break;  // unreachable: chunk 0 publishes PREFIX
      }
      __hip_atomic_store(&dseg[c], ((acc + total) & 0x3FFFFFFFu) | (2u << 30),
                         __ATOMIC_RELAXED, __HIP_MEMORY_SCOPE_AGENT);
    }
    baseS = acc;
  }
  __syncthreads();
  uint32_t run = baseS + ex;
  uint32_t* dst = Hbk + (size_t)sl * HL + e0;
#pragma unroll
  for (int i = 0; i < 16; ++i) {
    dst[i] = run;
    run += vals[i];
  }
}

// ---------- dual packed-u16 exclusive scan over 256 threads ----------
__device__ __forceinline__ void scan_pack2(uint32_t v0, uint32_t v1, uint32_t* s,
                                           uint32_t& ex0, uint32_t& ex1,
                                           uint32_t& tot0, uint32_t& tot1) {
  const int lane = threadIdx.x & 63, w = threadIdx.x >> 6;
  uint32_t a = v0, b = v1;
#pragma unroll
  for (int o = 1; o < 64; o <<= 1) {
    uint32_t na = __shfl_up(a, (unsigned)o, 64);
    uint32_t nb = __shfl_up(b, (unsigned)o, 64);
    if (lane >= o) { a += na; b += nb; }
  }
  if (lane == 63) { s[w] = a; s[4 + w] = b; }
  __syncthreads();   // also the read/write fence for the in-place split
  if (threadIdx.x == 0) {
    uint32_t r0 = 0, r1 = 0;
#pragma unroll
    for (int i = 0; i < 4; ++i) {
      uint32_t q0 = s[i], q1 = s[4 + i];
      s[i] = r0; s[4 + i] = r1;
      r0 += q0; r1 += q1;
    }
    s[8] = r0; s[9] = r1;
  }
  __syncthreads();
  ex0 = a - v0 + s[w];
  ex1 = b - v1 + s[4 + w];
  tot0 = s[8]; tot1 = s[9];
  __syncthreads();  // protect scratch before next-round reuse
}

// ---------- stable partition pass (templated digit P, output MODE) ----------
// MODE 0: write pairs to dst; MODE 1: tsorted[dest]=val; MODE 2: out[idx]=tsorted[dest]
template <int P, int MODE>
__global__ __launch_bounds__(256) void part_k(const uint64_t* __restrict__ src,
                                              uint64_t* __restrict__ dst,
                                              const uint32_t* __restrict__ Hbk,
                                              float* __restrict__ tsorted,
                                              float* __restrict__ out,
                                              int segbase, int slbase) {
  __shared__ uint64_t buf[SBUF];       // single tile buffer (in-place split)
  __shared__ uint32_t ldsStart[RADIX];
  __shared__ uint32_t ldsBase[RADIX];
  __shared__ uint32_t scanS[12];
  const int t = threadIdx.x;
  const int blk = blockIdx.x;
  const int sl = slbase + blockIdx.y;
  const int seg = segbase + sl;
  const uint64_t* ps = src + (size_t)sl * SEG_N + (size_t)blk * TILE;

  // hoisted: per-digit global base (uncoalesced gather; latency hides under
  // the sort rounds — first consumer is the emit loop at the end)
  ldsBase[t] = Hbk[(size_t)sl * HL + (size_t)t * NBLK + blk];

  // stage tile into LDS (coalesced), padded layout
#pragma unroll
  for (int r = 0; r < EPT; ++r) buf[SIDX(r * 256 + t)] = ps[r * 256 + t];
  __syncthreads();

  // 4 stable 2-bit split rounds (LSB-first within the byte), IN PLACE:
  // every thread reads its EPT elements into registers BEFORE the first
  // barrier inside scan_pack2; all scatter writes happen AFTER it.
  uint64_t e[EPT];
#pragma unroll
  for (int rnd = 0; rnd < 4; ++rnd) {
#pragma unroll
    for (int j = 0; j < EPT; ++j) e[j] = buf[SIDX(t * EPT + j)];
    uint32_t cnt[4] = {0u, 0u, 0u, 0u};
#pragma unroll
    for (int j = 0; j < EPT; ++j) {
      uint32_t d2 = (uint32_t)(e[j] >> (32 + 8 * P + 2 * rnd)) & 3u;
      cnt[d2]++;
    }
    uint32_t p0 = cnt[0] | (cnt[1] << 16);
    uint32_t p1 = cnt[2] | (cnt[3] << 16);
    uint32_t ex0, ex1, tot0, tot1;
    scan_pack2(p0, p1, scanS, ex0, ex1, tot0, tot1);
    uint32_t t0 = tot0 & 0xffffu, t1 = tot0 >> 16, t2 = tot1 & 0xffffu;
    uint32_t pos[4];
    pos[0] = (ex0 & 0xffffu);
    pos[1] = t0 + (ex0 >> 16);
    pos[2] = t0 + t1 + (ex1 & 0xffffu);
    pos[3] = t0 + t1 + t2 + (ex1 >> 16);
#pragma unroll
    for (int j = 0; j < EPT; ++j) {
      uint32_t d2 = (uint32_t)(e[j] >> (32 + 8 * P + 2 * rnd)) & 3u;
      buf[SIDX(pos[d2]++)] = e[j];
    }
    __syncthreads();
  }
  // buf: tile stably sorted by digit P

  // per-digit local starts via sorted-run boundary detection
  const uint8_t* b8 = reinterpret_cast<const uint8_t*>(buf);
#pragma unroll
  for (int r = 0; r < EPT; ++r) {
    uint32_t s = (uint32_t)(r * 256 + t);
    e[r] = buf[SIDX(s)];
    uint32_t d = (uint32_t)(e[r] >> (32 + 8 * P)) & 255u;
    uint32_t dp = (s == 0) ? 0x100u
                           : (uint32_t)b8[(size_t)SIDX(s - 1) * 8 + 4 + P];
    if (d != dp) ldsStart[d] = s;
  }
  __syncthreads();

  // emit in sorted-tile order: digit runs -> contiguous global ranges
#pragma unroll
  for (int r = 0; r < EPT; ++r) {
    uint32_t s = (uint32_t)(r * 256 + t);
    uint64_t el = e[r];
    uint32_t key = (uint32_t)(el >> 32);
    uint32_t d = (key >> (8 * P)) & 255u;
    uint32_t dest = ldsBase[d] + s - ldsStart[d];
    if (MODE == 0) {
      dst[(size_t)sl * SEG_N + dest] = el;
    } else if (MODE == 1) {
      tsorted[dest] = finv(key);
    } else {
      out[(size_t)(seg - 1) * SEG_N + (uint32_t)el] = tsorted[dest];
    }
  }
}

// ---------------------------------------------------------------------------
extern "C" void kernel_launch(void* const* d_in, const int* in_sizes, int n_in,
                              void* d_out, int out_size, void* d_ws, size_t ws_size,
                              hipStream_t stream) {
  const float* x = (const float*)d_in[0];
  const float* tmpl = (const float*)d_in[1];
  float* out = (float*)d_out;

  auto need = [](int nb) -> size_t {
    return (size_t)nb * ((size_t)SEG_N * 16 + (size_t)HL * 8 + 4096) +
           (size_t)SEG_N * 4 + 16384;
  };
  const int nb = (ws_size >= need(9)) ? 9 : (ws_size >= need(3)) ? 3 : 1;

  uint8_t* w = (uint8_t*)d_ws;
  size_t off = 0;
  auto carve = [&](size_t bytes) -> void* {
    void* p = w + off;
    off = (off + bytes + 255) & ~(size_t)255;
    return p;
  };
  uint64_t* pairsA = (uint64_t*)carve((size_t)nb * SEG_N * 8);
  uint64_t* pairsB = (uint64_t*)carve((size_t)nb * SEG_N * 8);
  uint32_t* Hkb = (uint32_t*)carve((size_t)nb * HL * 4);
  uint32_t* Hbk = (uint32_t*)carve((size_t)nb * HL * 4);
  uint32_t* desc = (uint32_t*)carve((size_t)4 * nb * SNB * 4);
  float* tsorted = (float*)carve((size_t)SEG_N * 4);

  for (int g = 0; g < NSEG; g += nb) {
    const dim3 gi(NBLK, nb);
    const dim3 gs(SNB, nb);

    hipMemsetAsync(desc, 0, (size_t)4 * nb * SNB * 4, stream);

    // pass 0 (digit-0 hist fused into init)
    init_k<<<gi, 256, 0, stream>>>(x, tmpl, g, pairsA, Hkb);
    scanT_k<<<gs, 256, 0, stream>>>(Hkb, Hbk, desc + 0 * nb * SNB);
    part_k<0, 0><<<gi, 256, 0, stream>>>(pairsA, pairsB, Hbk, tsorted, out, g, 0);
    // pass 1
    hist_k<<<gi, 256, 0, stream>>>(pairsB, Hkb, 1);
    scanT_k<<<gs, 256, 0, stream>>>(Hkb, Hbk, desc + 1 * nb * SNB);
    part_k<1, 0><<<gi, 256, 0, stream>>>(pairsB, pairsA, Hbk, tsorted, out, g, 0);
    // pass 2
    hist_k<<<gi, 256, 0, stream>>>(pairsA, Hkb, 2);
    scanT_k<<<gs, 256, 0, stream>>>(Hkb, Hbk, desc + 2 * nb * SNB);
    part_k<2, 0><<<gi, 256, 0, stream>>>(pairsA, pairsB, Hbk, tsorted, out, g, 0);
    // pass 3 (fused epilogue)
    hist_k<<<gi, 256, 0, stream>>>(pairsB, Hkb, 3);
    scanT_k<<<gs, 256, 0, stream>>>(Hkb, Hbk, desc + 3 * nb * SNB);
    if (g == 0) {
      part_k<3, 1><<<dim3(NBLK, 1), 256, 0, stream>>>(pairsB, pairsA, Hbk,
                                                      tsorted, out, g, 0);
      if (nb > 1)
        part_k<3, 2><<<dim3(NBLK, nb - 1), 256, 0, stream>>>(pairsB, pairsA, Hbk,
                                                             tsorted, out, g, 1);
    } else {
      part_k<3, 2><<<dim3(NBLK, nb), 256, 0, stream>>>(pairsB, pairsA, Hbk,
                                                       tsorted, out, g, 0);
    }
  }
}

// Round 9
// 1104.402 us; speedup vs baseline: 1.1205x; 1.1205x over previous
//
#include <hip/hip_runtime.h>
#include <stdint.h>

// HistMatching via stable LSD radix sort (4 x 8-bit passes) of (key32,idx32)
// u64 pairs per segment. Stability via per-(bin,block) histogram matrix +
// exclusive scan. Final pass fuses the epilogue: template -> tsorted[dest]=val;
// samples -> out[idx]=tsorted[dest].
//
// R1: part_k single-LDS-buffer in-place split (4x2-bit rounds), run-boundary
//     starts, hoisted base gather. 117us/dispatch verified. TILE=4096 verified
//     optimal (R7: 8192 regressed; R4: SoA regressed; R5: 4-bit regressed).
// R2/R3/R6 (REVERTED): fused global-atomic hist / onesweep / waterfall.
// R7 (REVERTED): TILE=8192 — write amplification is digit-count-driven, not
//     run-length-driven; occupancy loss dominated.
// R8: auxiliary-traffic cut. (a) init_k DELETED: part_k<0,MODE=3> reads x
//     directly (fkey on the fly, implicit idx), hist0_k (94MB read) supplies
//     the digit-0 histogram. (b) hists write TRANSPOSED [bin][blk] directly
//     (adjacent blocks hit the same line -> L2 write-combining). (c) scanT_k
//     is now a coalesced linear in-place scan + 8-wide batched lookback —
//     the 94MB/dispatch strided gather is gone.
// R9: identical resubmit of R8 (previous bench died to container-acquisition
//     infra failure before producing any data).

#define SEG_N 2621440            // 128*160*128
#define NSEG 9                   // template + 8 samples
#define TILE 4096
#define NBLK (SEG_N / TILE)      // 640 blocks per segment
#define RADIX 256
#define HL (RADIX * NBLK)        // 163840 histogram-matrix entries per seg
#define SCHUNK 4096
#define SNB (HL / SCHUNK)        // 40 scan chunks per seg
#define SBUF (TILE + (TILE >> 4))  // 4352 u64, padded 1-per-16

// monotone f32 -> u32 (order-preserving)
__device__ __forceinline__ uint32_t fkey(float f) {
  uint32_t b = __float_as_uint(f);
  return b ^ ((b & 0x80000000u) ? 0xFFFFFFFFu : 0x80000000u);
}
__device__ __forceinline__ float finv(uint32_t u) {
  uint32_t b = u ^ ((u & 0x80000000u) ? 0x80000000u : 0xFFFFFFFFu);
  return __uint_as_float(b);
}
__device__ __forceinline__ uint32_t SIDX(uint32_t i) { return i + (i >> 4); }

// ---------- digit-0 histogram straight from the float input ----------
__global__ __launch_bounds__(256) void hist0_k(const float* __restrict__ x,
                                               const float* __restrict__ tmpl,
                                               int segbase,
                                               uint32_t* __restrict__ Hbk) {
  __shared__ uint32_t hw[4 * RADIX];   // per-wave replicated
  const int t = threadIdx.x;
  const int blk = blockIdx.x;
  const int sl = blockIdx.y;
  const int seg = segbase + sl;
  const float* src = (seg == 0) ? tmpl : (x + (size_t)(seg - 1) * SEG_N);
  hw[t] = 0; hw[t + 256] = 0; hw[t + 512] = 0; hw[t + 768] = 0;
  __syncthreads();
  const int w = t >> 6;
  const float4* s4 = reinterpret_cast<const float4*>(src + blk * TILE);
#pragma unroll
  for (int r = 0; r < 4; ++r) {
    float4 v = s4[r * 256 + t];
    float f[4] = {v.x, v.y, v.z, v.w};
#pragma unroll
    for (int c = 0; c < 4; ++c)
      atomicAdd(&hw[w * 256 + (fkey(f[c]) & 255u)], 1u);
  }
  __syncthreads();
  // transposed [bin][blk] write: adjacent blk -> adjacent words, L2-combined
  Hbk[(size_t)sl * HL + (size_t)t * NBLK + blk] =
      hw[t] + hw[t + 256] + hw[t + 512] + hw[t + 768];
}

// ---------- histogram of digit p over current pairs (transposed write) ----
__global__ __launch_bounds__(256) void hist_k(const uint64_t* __restrict__ pairs,
                                              uint32_t* __restrict__ Hbk, int p) {
  __shared__ uint32_t hw[4 * RADIX];   // per-wave replicated
  const int t = threadIdx.x;
  const int blk = blockIdx.x;
  const int sl = blockIdx.y;
  hw[t] = 0; hw[t + 256] = 0; hw[t + 512] = 0; hw[t + 768] = 0;
  __syncthreads();
  const int w = t >> 6;
  const int sh = 32 + 8 * p;
  const ulonglong2* pc = reinterpret_cast<const ulonglong2*>(
      pairs + (size_t)sl * SEG_N + (size_t)blk * TILE);
#pragma unroll
  for (int r = 0; r < 8; ++r) {
    ulonglong2 v = pc[r * 256 + t];
    atomicAdd(&hw[w * 256 + ((uint32_t)(v.x >> sh) & 255u)], 1u);
    atomicAdd(&hw[w * 256 + ((uint32_t)(v.y >> sh) & 255u)], 1u);
  }
  __syncthreads();
  Hbk[(size_t)sl * HL + (size_t)t * NBLK + blk] =
      hw[t] + hw[t + 256] + hw[t + 512] + hw[t + 768];
}

// ---------- coalesced in-place exclusive scan + decoupled lookback ----------
// Hbk is already [bin][blk]; scan the flat HL sequence per segment in place.
// 40 chunks/segment, all co-resident => flag-spin lookback is deadlock-free.
// desc word = flag[31:30] | value[29:0], relaxed agent-scope.
__global__ __launch_bounds__(256) void scanT_k(uint32_t* __restrict__ Hbk,
                                               uint32_t* __restrict__ desc) {
  __shared__ uint32_t lds[256];
  __shared__ uint32_t baseS;
  const int t = threadIdx.x;
  const int c = blockIdx.x;          // 0..SNB-1
  const int sl = blockIdx.y;
  uint32_t* base = Hbk + (size_t)sl * HL + (size_t)c * SCHUNK + (size_t)t * 16;
  uint4* p4 = reinterpret_cast<uint4*>(base);
  uint4 a[4];
  uint32_t s = 0;
#pragma unroll
  for (int k = 0; k < 4; ++k) {
    a[k] = p4[k];
    s += a[k].x + a[k].y + a[k].z + a[k].w;
  }
  // block-wide scan of per-thread sums (Hillis-Steele)
  lds[t] = s;
  __syncthreads();
#pragma unroll
  for (int off = 1; off < 256; off <<= 1) {
    uint32_t v = (t >= off) ? lds[t - off] : 0u;
    __syncthreads();
    lds[t] += v;
    __syncthreads();
  }
  const uint32_t incl = lds[t];
  const uint32_t total = lds[255];
  const uint32_t ex = incl - s;

  uint32_t* dseg = desc + sl * SNB;
  if (t == 0) {
    __hip_atomic_store(&dseg[c], (total & 0x3FFFFFFFu) |
                                     ((c == 0 ? 2u : 1u) << 30),
                       __ATOMIC_RELAXED, __HIP_MEMORY_SCOPE_AGENT);
    uint32_t acc = 0;
    if (c > 0) {
      int b = c - 1;
      bool done = false;
      while (!done) {
        uint32_t dv[8];
        const int n = (b >= 7) ? 8 : (b + 1);
#pragma unroll
        for (int i = 0; i < 8; ++i)
          if (i < n)
            dv[i] = __hip_atomic_load(&dseg[b - i], __ATOMIC_RELAXED,
                                      __HIP_MEMORY_SCOPE_AGENT);
        for (int i = 0; i < n; ++i) {
          uint32_t v = dv[i];
          while ((v >> 30) == 0u)
            v = __hip_atomic_load(&dseg[b - i], __ATOMIC_RELAXED,
                                  __HIP_MEMORY_SCOPE_AGENT);
          acc += v & 0x3FFFFFFFu;
          if ((v >> 30) == 2u) { done = true; break; }
        }
        b -= n;
        if (!done && b < 0) break;  // unreachable: chunk 0 publishes PREFIX
      }
      __hip_atomic_store(&dseg[c], ((acc + total) & 0x3FFFFFFFu) | (2u << 30),
                         __ATOMIC_RELAXED, __HIP_MEMORY_SCOPE_AGENT);
    }
    baseS = acc;
  }
  __syncthreads();
  uint32_t run = baseS + ex;
#pragma unroll
  for (int k = 0; k < 4; ++k) {
    uint4 o;
    o.x = run; run += a[k].x;
    o.y = run; run += a[k].y;
    o.z = run; run += a[k].z;
    o.w = run; run += a[k].w;
    p4[k] = o;
  }
}

// ---------- dual packed-u16 exclusive scan over 256 threads ----------
__device__ __forceinline__ void scan_pack2(uint32_t v0, uint32_t v1, uint32_t* s,
                                           uint32_t& ex0, uint32_t& ex1,
                                           uint32_t& tot0, uint32_t& tot1) {
  const int lane = threadIdx.x & 63, w = threadIdx.x >> 6;
  uint32_t a = v0, b = v1;
#pragma unroll
  for (int o = 1; o < 64; o <<= 1) {
    uint32_t na = __shfl_up(a, (unsigned)o, 64);
    uint32_t nb = __shfl_up(b, (unsigned)o, 64);
    if (lane >= o) { a += na; b += nb; }
  }
  if (lane == 63) { s[w] = a; s[4 + w] = b; }
  __syncthreads();   // also the read/write fence for the in-place split
  if (threadIdx.x == 0) {
    uint32_t r0 = 0, r1 = 0;
#pragma unroll
    for (int i = 0; i < 4; ++i) {
      uint32_t q0 = s[i], q1 = s[4 + i];
      s[i] = r0; s[4 + i] = r1;
      r0 += q0; r1 += q1;
    }
    s[8] = r0; s[9] = r1;
  }
  __syncthreads();
  ex0 = a - v0 + s[w];
  ex1 = b - v1 + s[4 + w];
  tot0 = s[8]; tot1 = s[9];
  __syncthreads();  // protect scratch before next-round reuse
}

// ---------- stable partition pass (templated digit P, output MODE) ----------
// MODE 0: pairs->dst; MODE 1: tsorted[dest]=val; MODE 2: out[idx]=tsorted[dest]
// MODE 3: pass-0 variant — reads FLOATS from x/tmpl, builds keys on the fly
//         (idx implicit from source position), writes pairs to dst.
template <int P, int MODE>
__global__ __launch_bounds__(256) void part_k(const uint64_t* __restrict__ src,
                                              uint64_t* __restrict__ dst,
                                              const uint32_t* __restrict__ Hbk,
                                              const float* __restrict__ xin,
                                              const float* __restrict__ tmplin,
                                              float* __restrict__ tsorted,
                                              float* __restrict__ out,
                                              int segbase, int slbase) {
  __shared__ uint64_t buf[SBUF];       // single tile buffer (in-place split)
  __shared__ uint32_t ldsStart[RADIX];
  __shared__ uint32_t ldsBase[RADIX];
  __shared__ uint32_t scanS[12];
  const int t = threadIdx.x;
  const int blk = blockIdx.x;
  const int sl = slbase + blockIdx.y;
  const int seg = segbase + sl;

  // hoisted: per-digit global base (uncoalesced gather; latency hides under
  // the sort rounds — first consumer is the emit loop at the end)
  ldsBase[t] = Hbk[(size_t)sl * HL + (size_t)t * NBLK + blk];

  // stage tile into LDS (coalesced), padded layout
  if (MODE == 3) {
    const float* fsrc =
        (seg == 0) ? tmplin : (xin + (size_t)(seg - 1) * SEG_N);
    const float4* s4 = reinterpret_cast<const float4*>(fsrc + blk * TILE);
    const uint32_t base = (uint32_t)blk * TILE;
#pragma unroll
    for (int r = 0; r < 4; ++r) {
      float4 v = s4[r * 256 + t];
      uint32_t i0 = base + (uint32_t)(r * 256 + t) * 4u;
      float f[4] = {v.x, v.y, v.z, v.w};
#pragma unroll
      for (int c = 0; c < 4; ++c) {
        uint32_t k = fkey(f[c]);
        buf[SIDX((uint32_t)(r * 256 + t) * 4u + (uint32_t)c)] =
            ((uint64_t)k << 32) | (uint64_t)(i0 + c);
      }
    }
  } else {
    const uint64_t* ps = src + (size_t)sl * SEG_N + (size_t)blk * TILE;
#pragma unroll
    for (int r = 0; r < 16; ++r) buf[SIDX(r * 256 + t)] = ps[r * 256 + t];
  }
  __syncthreads();

  // 4 stable 2-bit split rounds (LSB-first within the byte), IN PLACE:
  // every thread reads its 16 elements into registers BEFORE the first
  // barrier inside scan_pack2; all scatter writes happen AFTER it.
  uint64_t e[16];
#pragma unroll
  for (int rnd = 0; rnd < 4; ++rnd) {
#pragma unroll
    for (int j = 0; j < 16; ++j) e[j] = buf[SIDX(t * 16 + j)];
    uint32_t cnt[4] = {0u, 0u, 0u, 0u};
#pragma unroll
    for (int j = 0; j < 16; ++j) {
      uint32_t d2 = (uint32_t)(e[j] >> (32 + 8 * P + 2 * rnd)) & 3u;
      cnt[d2]++;
    }
    uint32_t p0 = cnt[0] | (cnt[1] << 16);
    uint32_t p1 = cnt[2] | (cnt[3] << 16);
    uint32_t ex0, ex1, tot0, tot1;
    scan_pack2(p0, p1, scanS, ex0, ex1, tot0, tot1);
    uint32_t t0 = tot0 & 0xffffu, t1 = tot0 >> 16, t2 = tot1 & 0xffffu;
    uint32_t pos[4];
    pos[0] = (ex0 & 0xffffu);
    pos[1] = t0 + (ex0 >> 16);
    pos[2] = t0 + t1 + (ex1 & 0xffffu);
    pos[3] = t0 + t1 + t2 + (ex1 >> 16);
#pragma unroll
    for (int j = 0; j < 16; ++j) {
      uint32_t d2 = (uint32_t)(e[j] >> (32 + 8 * P + 2 * rnd)) & 3u;
      buf[SIDX(pos[d2]++)] = e[j];
    }
    __syncthreads();
  }
  // buf: tile stably sorted by digit P

  // per-digit local starts via sorted-run boundary detection
  const uint8_t* b8 = reinterpret_cast<const uint8_t*>(buf);
#pragma unroll
  for (int r = 0; r < 16; ++r) {
    uint32_t s = (uint32_t)(r * 256 + t);
    e[r] = buf[SIDX(s)];
    uint32_t d = (uint32_t)(e[r] >> (32 + 8 * P)) & 255u;
    uint32_t dp = (s == 0) ? 0x100u
                           : (uint32_t)b8[(size_t)SIDX(s - 1) * 8 + 4 + P];
    if (d != dp) ldsStart[d] = s;
  }
  __syncthreads();

  // emit in sorted-tile order: digit runs -> contiguous global ranges
#pragma unroll
  for (int r = 0; r < 16; ++r) {
    uint32_t s = (uint32_t)(r * 256 + t);
    uint64_t el = e[r];
    uint32_t key = (uint32_t)(el >> 32);
    uint32_t d = (key >> (8 * P)) & 255u;
    uint32_t dest = ldsBase[d] + s - ldsStart[d];
    if (MODE == 0 || MODE == 3) {
      dst[(size_t)sl * SEG_N + dest] = el;
    } else if (MODE == 1) {
      tsorted[dest] = finv(key);
    } else {
      out[(size_t)(seg - 1) * SEG_N + (uint32_t)el] = tsorted[dest];
    }
  }
}

// ---------------------------------------------------------------------------
extern "C" void kernel_launch(void* const* d_in, const int* in_sizes, int n_in,
                              void* d_out, int out_size, void* d_ws, size_t ws_size,
                              hipStream_t stream) {
  const float* x = (const float*)d_in[0];
  const float* tmpl = (const float*)d_in[1];
  float* out = (float*)d_out;

  auto need = [](int nb) -> size_t {
    return (size_t)nb * ((size_t)SEG_N * 16 + (size_t)HL * 4 + 4096) +
           (size_t)SEG_N * 4 + 16384;
  };
  const int nb = (ws_size >= need(9)) ? 9 : (ws_size >= need(3)) ? 3 : 1;

  uint8_t* w = (uint8_t*)d_ws;
  size_t off = 0;
  auto carve = [&](size_t bytes) -> void* {
    void* p = w + off;
    off = (off + bytes + 255) & ~(size_t)255;
    return p;
  };
  uint64_t* pairsA = (uint64_t*)carve((size_t)nb * SEG_N * 8);
  uint64_t* pairsB = (uint64_t*)carve((size_t)nb * SEG_N * 8);
  uint32_t* Hbk = (uint32_t*)carve((size_t)nb * HL * 4);
  uint32_t* desc = (uint32_t*)carve((size_t)4 * nb * SNB * 4);
  float* tsorted = (float*)carve((size_t)SEG_N * 4);

  for (int g = 0; g < NSEG; g += nb) {
    const dim3 gi(NBLK, nb);
    const dim3 gs(SNB, nb);

    hipMemsetAsync(desc, 0, (size_t)4 * nb * SNB * 4, stream);

    // pass 0: hist from floats, part reads floats directly (init_k deleted)
    hist0_k<<<gi, 256, 0, stream>>>(x, tmpl, g, Hbk);
    scanT_k<<<gs, 256, 0, stream>>>(Hbk, desc + 0 * nb * SNB);
    part_k<0, 3><<<gi, 256, 0, stream>>>(nullptr, pairsA, Hbk, x, tmpl,
                                         tsorted, out, g, 0);
    // pass 1
    hist_k<<<gi, 256, 0, stream>>>(pairsA, Hbk, 1);
    scanT_k<<<gs, 256, 0, stream>>>(Hbk, desc + 1 * nb * SNB);
    part_k<1, 0><<<gi, 256, 0, stream>>>(pairsA, pairsB, Hbk, nullptr, nullptr,
                                         tsorted, out, g, 0);
    // pass 2
    hist_k<<<gi, 256, 0, stream>>>(pairsB, Hbk, 2);
    scanT_k<<<gs, 256, 0, stream>>>(Hbk, desc + 2 * nb * SNB);
    part_k<2, 0><<<gi, 256, 0, stream>>>(pairsB, pairsA, Hbk, nullptr, nullptr,
                                         tsorted, out, g, 0);
    // pass 3 (fused epilogue; no pair write)
    hist_k<<<gi, 256, 0, stream>>>(pairsA, Hbk, 3);
    scanT_k<<<gs, 256, 0, stream>>>(Hbk, desc + 3 * nb * SNB);
    if (g == 0) {
      part_k<3, 1><<<dim3(NBLK, 1), 256, 0, stream>>>(
          pairsA, pairsB, Hbk, nullptr, nullptr, tsorted, out, g, 0);
      if (nb > 1)
        part_k<3, 2><<<dim3(NBLK, nb - 1), 256, 0, stream>>>(
            pairsA, pairsB, Hbk, nullptr, nullptr, tsorted, out, g, 1);
    } else {
      part_k<3, 2><<<dim3(NBLK, nb), 256, 0, stream>>>(
          pairsA, pairsB, Hbk, nullptr, nullptr, tsorted, out, g, 0);
    }
  }
}